// Round 4
// baseline (1469.812 us; speedup 1.0000x reference)
//
#include <hip/hip_runtime.h>
#include <hip/hip_bf16.h>
#include <math.h>

#define NTOT 65536
#define KCB  2048
#define CDIM 256
#define HW   1024

#define OUT_LOSS 16777216
#define OUT_PERP 16777217
#define OUT_ENC  16777218

// bf16 staging lives in the (later overwritten) encodings output region:
#define ZB_OFF_F  16777232   // 64B-aligned; 33.5 MB zb [65536][256] bf16
#define CBB_OFF_F 33554448   // 1 MB cbb [2048][256] bf16

// workspace byte offsets
#define WS_SROW 0                       // 65536 float
#define WS_CK   262144                  // 2048 float
#define WS_IDX  270336                  // 65536 int
#define WS_CNT  532480                  // 2048 int
#define WS_PART 540672                  // 1024 double

#define MARGIN 3e-3f
#define WCAP 1024

typedef __attribute__((ext_vector_type(8))) short short8;
typedef __attribute__((ext_vector_type(4))) float f32x4;

// order-preserving float<->uint key (handles negative d~)
__device__ inline unsigned enc_f(float x) {
    unsigned u = __float_as_uint(x);
    return (u & 0x80000000u) ? ~u : (u | 0x80000000u);
}
__device__ inline float dec_f(unsigned e) {
    unsigned u = (e & 0x80000000u) ? (e ^ 0x80000000u) : ~e;
    return __uint_as_float(u);
}

__device__ inline void lds_min_u64(unsigned long long* p, unsigned long long v) {
    unsigned long long old = *p;
    while (v < old) {
        unsigned long long assumed = old;
        old = atomicCAS(p, assumed, v);
        if (old == assumed) break;
    }
}

// merged prep: blocks [0,512) cb->bf16+norms+hist-zero; [512,768) rownorm; [768,4864) z->bf16 transpose
__global__ __launch_bounds__(256) void k_prep(const float* __restrict__ z, const float* __restrict__ cb,
                                              ushort* __restrict__ zb, ushort* __restrict__ cbb,
                                              float* __restrict__ ck, float* __restrict__ srow,
                                              int* __restrict__ cntK) {
    __shared__ float tile[64][65];
    const int tid = threadIdx.x;
    const int bid = blockIdx.x;
    if (bid < 512) {
        int wv = tid >> 6, lane = tid & 63;
        int r = bid * 4 + wv;
        const float* row = cb + (size_t)r * CDIM;
        float4 v = *(const float4*)(row + lane * 4);
        ushort4 o;
        __hip_bfloat16 h;
        h = __float2bfloat16(v.x); o.x = *(ushort*)&h;
        h = __float2bfloat16(v.y); o.y = *(ushort*)&h;
        h = __float2bfloat16(v.z); o.z = *(ushort*)&h;
        h = __float2bfloat16(v.w); o.w = *(ushort*)&h;
        *(ushort4*)(cbb + (size_t)r * CDIM + lane * 4) = o;
        float s = v.x*v.x + v.y*v.y + v.z*v.z + v.w*v.w;
        for (int off = 32; off >= 1; off >>= 1) s += __shfl_down(s, off, 64);
        if (lane == 0) ck[r] = s;
        if (lane == 1) cntK[r] = 0;
    } else if (bid < 768) {
        // srow: EXACT sequential-fma order validated in round 1
        int n = (bid - 512) * 256 + tid;
        int b = n >> 10, hw = n & 1023;
        const float* base = z + (size_t)b * (CDIM * HW) + hw;
        float s = 0.f;
#pragma unroll 8
        for (int c = 0; c < CDIM; ++c) { float v = base[(size_t)c * HW]; s = fmaf(v, v, s); }
        srow[n] = s;
    } else {
        int zbid = bid - 768;
        int hwT = zbid & 15, cT = (zbid >> 4) & 3, b = zbid >> 6;
        int c0 = cT * 64, hw0 = hwT * 64;
        int w = tid >> 6, hw = tid & 63;
#pragma unroll
        for (int l = 0; l < 16; ++l) {
            int c = l * 4 + w;
            tile[c][hw] = z[((size_t)b * CDIM + (c0 + c)) * HW + hw0 + hw];
        }
        __syncthreads();
        int r = tid >> 2, g = tid & 3;
        union { ushort u[16]; int4 v[2]; } pk;
#pragma unroll
        for (int j = 0; j < 16; ++j) {
            __hip_bfloat16 h = __float2bfloat16(tile[g * 16 + j][r]);
            pk.u[j] = *(ushort*)&h;
        }
        size_t n = (size_t)b * HW + hw0 + r;
        ushort* dst = zb + n * CDIM + c0 + g * 16;
        *(int4*)(dst) = pk.v[0];
        *(int4*)(dst + 8) = pk.v[1];
    }
}

__device__ __forceinline__ void tile_mfma(const ushort* __restrict__ cbb, int kb, int col, int quad,
                                          const short8 (&areg)[4][8], f32x4 (&acc)[4][2]) {
#pragma unroll
    for (int nt = 0; nt < 4; ++nt)
#pragma unroll
        for (int kt = 0; kt < 2; ++kt)
            acc[nt][kt] = (f32x4){0.f, 0.f, 0.f, 0.f};
#pragma unroll
    for (int kt = 0; kt < 2; ++kt) {
        short8 bfrag[8];
#pragma unroll
        for (int cs = 0; cs < 8; ++cs)
            bfrag[cs] = *(const short8*)(cbb + ((size_t)(kb + kt * 16 + col)) * CDIM + cs * 32 + quad * 8);
#pragma unroll
        for (int nt = 0; nt < 4; ++nt)
#pragma unroll
            for (int cs = 0; cs < 8; ++cs)
                acc[nt][kt] = __builtin_amdgcn_mfma_f32_16x16x32_bf16(areg[nt][cs], bfrag[cs], acc[nt][kt], 0, 0, 0);
    }
}

// ---- single-sweep MFMA prefilter: no barriers in k-loop, monotone LDS running min,
// ---- seeded thresholds, per-wave candidate buffers, exact fp32 rescore ----
__global__ __launch_bounds__(256, 3) void k_mfma_argmin(
    const ushort* __restrict__ zb, const ushort* __restrict__ cbb,
    const float* __restrict__ z, const float* __restrict__ cb,
    const float* __restrict__ srow, const float* __restrict__ ckg,
    int* __restrict__ indices, int* __restrict__ cntK)
{
    __shared__ unsigned rowminU[64];
    __shared__ int cand[4][WCAP];
    __shared__ int wcnt[4];
    __shared__ unsigned long long best[64];

    const int tid = threadIdx.x;
    const int w = tid >> 6, lane = tid & 63;
    const int col = lane & 15, quad = lane >> 4;
    const int n0 = blockIdx.x * 64;

    // A fragments: lane holds A[row=col][c=quad*8..+7] for 4 row-tiles
    short8 areg[4][8];
#pragma unroll
    for (int nt = 0; nt < 4; ++nt)
#pragma unroll
        for (int cs = 0; cs < 8; ++cs)
            areg[nt][cs] = *(const short8*)(zb + ((size_t)(n0 + nt * 16 + col)) * CDIM + cs * 32 + quad * 8);

    if (tid < 64) { rowminU[tid] = 0xFFFFFFFFu; best[tid] = ~0ull; }
    if (tid < 4) wcnt[tid] = 0;
    float gmin[16];
#pragma unroll
    for (int s = 0; s < 16; ++s) gmin[s] = INFINITY;
    __syncthreads();

    // seed pass: tile k0=0, update-only (prevents tile-0 candidate flood)
    {
        f32x4 acc[4][2];
        tile_mfma(cbb, w * 32, col, quad, areg, acc);
#pragma unroll
        for (int kt = 0; kt < 2; ++kt) {
            const float ckv = ckg[w * 32 + kt * 16 + col];
#pragma unroll
            for (int nt = 0; nt < 4; ++nt)
#pragma unroll
                for (int r = 0; r < 4; ++r) {
                    float dt = fmaf(-2.0f, acc[nt][kt][r], ckv);
                    const int s = nt * 4 + r;
                    if (dt < gmin[s]) {
                        gmin[s] = dt;
                        atomicMin(&rowminU[nt * 16 + quad * 4 + r], enc_f(dt));
                    }
                }
        }
    }
    __syncthreads();   // one-time: make seed visible everywhere (later staleness is superset-safe)

    // main sweep: fused update+collect, NO barriers
    for (int k0 = 0; k0 < KCB; k0 += 128) {
        const int kb = k0 + w * 32;
        // refresh thresholds from LDS (monotone: any stale value >= final min)
#pragma unroll
        for (int s = 0; s < 16; ++s) {
            int row = (s >> 2) * 16 + quad * 4 + (s & 3);
            gmin[s] = fminf(gmin[s], dec_f(rowminU[row]));
        }
        f32x4 acc[4][2];
        tile_mfma(cbb, kb, col, quad, areg, acc);
#pragma unroll
        for (int kt = 0; kt < 2; ++kt) {
            const int k = kb + kt * 16 + col;
            const float ckv = ckg[k];
#pragma unroll
            for (int nt = 0; nt < 4; ++nt)
#pragma unroll
                for (int r = 0; r < 4; ++r) {
                    float dt = fmaf(-2.0f, acc[nt][kt][r], ckv);
                    const int s = nt * 4 + r;
                    const int row = nt * 16 + quad * 4 + r;
                    if (dt < gmin[s]) {
                        gmin[s] = dt;
                        atomicMin(&rowminU[row], enc_f(dt));
                    }
                    if (dt <= gmin[s] + MARGIN) {
                        int p = atomicAdd(&wcnt[w], 1);
                        if (p < WCAP) cand[w][p] = (row << 16) | k;
                    }
                }
        }
    }
    __syncthreads();

    // overflow (expected never): re-collect with final thresholds
    if (wcnt[0] > WCAP || wcnt[1] > WCAP || wcnt[2] > WCAP || wcnt[3] > WCAP) {
        if (tid < 4) wcnt[tid] = 0;
        __syncthreads();
        float thr[16];
#pragma unroll
        for (int s = 0; s < 16; ++s)
            thr[s] = dec_f(rowminU[(s >> 2) * 16 + quad * 4 + (s & 3)]) + MARGIN;
        for (int k0 = 0; k0 < KCB; k0 += 128) {
            const int kb = k0 + w * 32;
            f32x4 acc[4][2];
            tile_mfma(cbb, kb, col, quad, areg, acc);
#pragma unroll
            for (int kt = 0; kt < 2; ++kt) {
                const int k = kb + kt * 16 + col;
                const float ckv = ckg[k];
#pragma unroll
                for (int nt = 0; nt < 4; ++nt)
#pragma unroll
                    for (int r = 0; r < 4; ++r) {
                        float dt = fmaf(-2.0f, acc[nt][kt][r], ckv);
                        if (dt <= thr[nt * 4 + r]) {
                            int p = atomicAdd(&wcnt[w], 1);
                            if (p < WCAP) cand[w][p] = ((nt * 16 + quad * 4 + r) << 16) | k;
                        }
                    }
            }
        }
        __syncthreads();
    }

    // exact fp32 rescore (identical formula/order to round-1 validated kernel)
    const int b = n0 >> 10, hw0 = n0 & 1023;
    for (int w2 = 0; w2 < 4; ++w2) {
        const int nc = min(wcnt[w2], WCAP);
        for (int t = tid; t < nc; t += 256) {
            const int rc = cand[w2][t];
            const int row = rc >> 16, k = rc & 0xFFFF;
            const float* zp = z + (size_t)b * (CDIM * HW) + hw0 + row;
            const float* cp = cb + (size_t)k * CDIM;
            float m = 0.f;
#pragma unroll 8
            for (int c = 0; c < CDIM; ++c) m = fmaf(zp[(size_t)c << 10], cp[c], m);
            float d = (srow[n0 + row] - 2.0f * m) + ckg[k];   // 2m exact -> fma contraction bitwise-safe
            unsigned long long pk = ((unsigned long long)__float_as_uint(d) << 32) | (unsigned)k;
            lds_min_u64(&best[row], pk);   // d>=0: bit-order == float order; low bits: lowest-k tie
        }
    }
    __syncthreads();
    if (tid < 64) {
        int bk = (int)(best[tid] & 0xFFFFFFFFull);
        indices[n0 + tid] = bk;
        atomicAdd(&cntK[bk], 1);
    }
}

// coalesced gather: block owns 64 rows; stage their codebook rows in LDS transposed
// (stores/reads are wave-uniform in the c-group -> conflict-free at stride 64)
__global__ __launch_bounds__(256, 2) void k_gather(const float* __restrict__ z, const float* __restrict__ cb,
                                                   const int* __restrict__ idx, float* __restrict__ out0,
                                                   double* __restrict__ part) {
    __shared__ float qt[CDIM * 64];   // qt[c][n] 64 KB
    __shared__ double sh[256];
    const int tid = threadIdx.x;
    const int nl = tid & 63, cg = tid >> 6;
    const int n0 = blockIdx.x * 64;
    const int b = n0 >> 10, hw0 = n0 & 1023;
    const int k = idx[n0 + nl];
    const float* crow = cb + (size_t)k * CDIM + cg * 64;
#pragma unroll
    for (int j4 = 0; j4 < 16; ++j4) {
        float4 v = *(const float4*)(crow + j4 * 4);
        int c = cg * 64 + j4 * 4;
        qt[(c + 0) * 64 + nl] = v.x;
        qt[(c + 1) * 64 + nl] = v.y;
        qt[(c + 2) * 64 + nl] = v.z;
        qt[(c + 3) * 64 + nl] = v.w;
    }
    __syncthreads();
    double acc = 0.0;
    const size_t ebase = ((size_t)b * CDIM) * HW + hw0 + nl;
#pragma unroll 4
    for (int j = 0; j < 64; ++j) {
        int c = cg * 64 + j;
        size_t e = ebase + ((size_t)c << 10);
        float ze = z[e];
        float q = qt[c * 64 + nl];
        float d = q - ze;
        out0[e] = ze + d;
        acc += (double)d * (double)d;
    }
    sh[tid] = acc;
    __syncthreads();
    for (int s = 128; s > 0; s >>= 1) {
        if (tid < s) sh[tid] += sh[tid + s];
        __syncthreads();
    }
    if (tid == 0) part[blockIdx.x] = sh[0];
}

// fused zero + one-hot scatter over [OUT_LOSS, end) as float4 (16B-aligned anchor)
__global__ __launch_bounds__(256) void k_encodings(const int* __restrict__ idx, float4* __restrict__ p4,
                                                   float* __restrict__ tail) {
    __shared__ int sidx[17];
    const int tid = threadIdx.x;
    const size_t g0 = (size_t)blockIdx.x * 8192;
    const long f0 = 4L * (long)g0 - 2;
    int nlo = (int)(f0 >> 11); if (nlo < 0) nlo = 0;
    if (tid < 17) { int n = nlo + tid; sidx[tid] = (n < NTOT) ? idx[n] : -1; }
    __syncthreads();
    const float4 zv = make_float4(0.f, 0.f, 0.f, 0.f);
    for (int i = 0; i < 32; ++i) {
        size_t g = g0 + (size_t)i * 256 + tid;
        long fe = 4L * (long)g - 2;
        float4 v = zv;
        if (fe < 0) {
            // g==0: comps 0,1 = loss/perp (finalize rewrites), comps 2,3 = enc[n=0][k=0,1]
            int kk = sidx[0];
            if (kk == 0) v.z = 1.f;
            if (kk == 1) v.w = 1.f;
        } else {
            int n = (int)(fe >> 11);
            int k0c = (int)(fe & 2047);
            if (k0c >= 2045) {   // f4 straddles a row boundary
#pragma unroll
                for (int j = 0; j < 4; ++j) {
                    long fej = fe + j;
                    int nj = (int)(fej >> 11);
                    int kj = (int)(fej & 2047);
                    int li = nj - nlo;
                    int kk = (li >= 0 && li < 17) ? sidx[li] : -2;
                    ((float*)&v)[j] = (kk == kj) ? 1.f : 0.f;
                }
            } else {
                int d = sidx[n - nlo] - k0c;
                if (d >= 0 && d < 4) ((float*)&v)[d] = 1.f;
            }
        }
        p4[g] = v;
    }
    if (blockIdx.x == 0 && tid == 0) {
        // last 2 floats of out = enc[n=65535][k=2046,2047]
        int kk = idx[NTOT - 1];
        tail[0] = (kk == 2046) ? 1.f : 0.f;
        tail[1] = (kk == 2047) ? 1.f : 0.f;
    }
}

__global__ __launch_bounds__(256) void k_finalize(const double* __restrict__ part, const int* __restrict__ cnt,
                                                  float* __restrict__ out) {
    __shared__ double sh[256];
    double a = 0.0;
    for (int i = threadIdx.x; i < 1024; i += 256) a += part[i];
    sh[threadIdx.x] = a; __syncthreads();
    for (int s = 128; s > 0; s >>= 1) { if (threadIdx.x < s) sh[threadIdx.x] += sh[threadIdx.x + s]; __syncthreads(); }
    double total = sh[0];
    __syncthreads();
    double p = 0.0;
    for (int i = threadIdx.x; i < 2048; i += 256) {
        double pm = (double)cnt[i] / 65536.0;
        p += pm * log(pm + 1e-10);
    }
    sh[threadIdx.x] = p; __syncthreads();
    for (int s = 128; s > 0; s >>= 1) { if (threadIdx.x < s) sh[threadIdx.x] += sh[threadIdx.x + s]; __syncthreads(); }
    if (threadIdx.x == 0) {
        double mean = total / ((double)NTOT * (double)CDIM);
        out[OUT_LOSS] = (float)(mean * 1.25);
        out[OUT_PERP] = (float)exp(-sh[0]);
    }
}

extern "C" void kernel_launch(void* const* d_in, const int* in_sizes, int n_in,
                              void* d_out, int out_size, void* d_ws, size_t ws_size,
                              hipStream_t stream) {
    const float* z  = (const float*)d_in[0];
    const float* cb = (const float*)d_in[1];
    float* out = (float*)d_out;
    char* ws = (char*)d_ws;
    float*  srow = (float*)(ws + WS_SROW);
    float*  ck   = (float*)(ws + WS_CK);
    int*    idx  = (int*)(ws + WS_IDX);
    int*    cnt  = (int*)(ws + WS_CNT);
    double* part = (double*)(ws + WS_PART);
    ushort* zb  = (ushort*)(out + ZB_OFF_F);
    ushort* cbb = (ushort*)(out + CBB_OFF_F);

    hipLaunchKernelGGL(k_prep,        dim3(4864), dim3(256), 0, stream, z, cb, zb, cbb, ck, srow, cnt);
    hipLaunchKernelGGL(k_mfma_argmin, dim3(1024), dim3(256), 0, stream, zb, cbb, z, cb, srow, ck, idx, cnt);
    hipLaunchKernelGGL(k_gather,      dim3(1024), dim3(256), 0, stream, z, cb, idx, out, part);
    hipLaunchKernelGGL(k_encodings,   dim3(4096), dim3(256), 0, stream, idx, (float4*)(out + OUT_LOSS),
                       out + (OUT_LOSS + (size_t)33554432 * 4));
    hipLaunchKernelGGL(k_finalize,    dim3(1),    dim3(256), 0, stream, part, cnt, out);
}

// Round 5
// 1003.848 us; speedup vs baseline: 1.4642x; 1.4642x over previous
//
#include <hip/hip_runtime.h>
#include <hip/hip_bf16.h>
#include <math.h>

#define NTOT 65536
#define KCB  2048
#define CDIM 256
#define HW   1024

#define OUT_LOSS 16777216
#define OUT_PERP 16777217
#define OUT_ENC  16777218

// bf16 staging lives in the (later overwritten) encodings output region:
#define ZB_OFF_F  16777232   // 64B-aligned; 33.5 MB zb [65536][256] bf16
#define CBB_OFF_F 33554448   // 1 MB cbb [2048][256] bf16

// workspace byte offsets
#define WS_SROW 0                       // 65536 float
#define WS_CK   262144                  // 2048 float
#define WS_IDX  270336                  // 65536 int
#define WS_CNT  532480                  // 2048 int
#define WS_PART 540672                  // 1024 double

#define MARGIN 3e-3f
#define CAP 4096

typedef __attribute__((ext_vector_type(8))) short short8;
typedef __attribute__((ext_vector_type(4))) float f32x4;

// order-preserving float<->uint key (handles negative d~)
__device__ inline unsigned enc_f(float x) {
    unsigned u = __float_as_uint(x);
    return (u & 0x80000000u) ? ~u : (u | 0x80000000u);
}
__device__ inline float dec_f(unsigned e) {
    unsigned u = (e & 0x80000000u) ? (e ^ 0x80000000u) : ~e;
    return __uint_as_float(u);
}

__device__ inline void lds_min_u64(unsigned long long* p, unsigned long long v) {
    unsigned long long old = *p;
    while (v < old) {
        unsigned long long assumed = old;
        old = atomicCAS(p, assumed, v);
        if (old == assumed) break;
    }
}

// merged prep: blocks [0,512) cb->bf16+norms+hist-zero; [512,768) rownorm; [768,4864) z->bf16 transpose
__global__ __launch_bounds__(256) void k_prep(const float* __restrict__ z, const float* __restrict__ cb,
                                              ushort* __restrict__ zb, ushort* __restrict__ cbb,
                                              float* __restrict__ ck, float* __restrict__ srow,
                                              int* __restrict__ cntK) {
    __shared__ float tile[64][65];
    const int tid = threadIdx.x;
    const int bid = blockIdx.x;
    if (bid < 512) {
        int wv = tid >> 6, lane = tid & 63;
        int r = bid * 4 + wv;
        const float* row = cb + (size_t)r * CDIM;
        float4 v = *(const float4*)(row + lane * 4);
        ushort4 o;
        __hip_bfloat16 h;
        h = __float2bfloat16(v.x); o.x = *(ushort*)&h;
        h = __float2bfloat16(v.y); o.y = *(ushort*)&h;
        h = __float2bfloat16(v.z); o.z = *(ushort*)&h;
        h = __float2bfloat16(v.w); o.w = *(ushort*)&h;
        *(ushort4*)(cbb + (size_t)r * CDIM + lane * 4) = o;
        float s = v.x*v.x + v.y*v.y + v.z*v.z + v.w*v.w;
        for (int off = 32; off >= 1; off >>= 1) s += __shfl_down(s, off, 64);
        if (lane == 0) ck[r] = s;
        if (lane == 1) cntK[r] = 0;
    } else if (bid < 768) {
        // srow: EXACT sequential-fma order validated in round 1
        int n = (bid - 512) * 256 + tid;
        int b = n >> 10, hw = n & 1023;
        const float* base = z + (size_t)b * (CDIM * HW) + hw;
        float s = 0.f;
#pragma unroll 8
        for (int c = 0; c < CDIM; ++c) { float v = base[(size_t)c * HW]; s = fmaf(v, v, s); }
        srow[n] = s;
    } else {
        int zbid = bid - 768;
        int hwT = zbid & 15, cT = (zbid >> 4) & 3, b = zbid >> 6;
        int c0 = cT * 64, hw0 = hwT * 64;
        int w = tid >> 6, hw = tid & 63;
#pragma unroll
        for (int l = 0; l < 16; ++l) {
            int c = l * 4 + w;
            tile[c][hw] = z[((size_t)b * CDIM + (c0 + c)) * HW + hw0 + hw];
        }
        __syncthreads();
        int r = tid >> 2, g = tid & 3;
        union { ushort u[16]; int4 v[2]; } pk;
#pragma unroll
        for (int j = 0; j < 16; ++j) {
            __hip_bfloat16 h = __float2bfloat16(tile[g * 16 + j][r]);
            pk.u[j] = *(ushort*)&h;
        }
        size_t n = (size_t)b * HW + hw0 + r;
        ushort* dst = zb + n * CDIM + c0 + g * 16;
        *(int4*)(dst) = pk.v[0];
        *(int4*)(dst + 8) = pk.v[1];
    }
}

__device__ __forceinline__ void tile_mfma(const ushort* __restrict__ cbb, int kb, int col, int quad,
                                          const short8 (&areg)[4][8], f32x4 (&acc)[4][2]) {
#pragma unroll
    for (int nt = 0; nt < 4; ++nt)
#pragma unroll
        for (int kt = 0; kt < 2; ++kt)
            acc[nt][kt] = (f32x4){0.f, 0.f, 0.f, 0.f};
#pragma unroll
    for (int kt = 0; kt < 2; ++kt) {
        short8 bfrag[8];
#pragma unroll
        for (int cs = 0; cs < 8; ++cs)
            bfrag[cs] = *(const short8*)(cbb + ((size_t)(kb + kt * 16 + col)) * CDIM + cs * 32 + quad * 8);
#pragma unroll
        for (int nt = 0; nt < 4; ++nt)
#pragma unroll
            for (int cs = 0; cs < 8; ++cs)
                acc[nt][kt] = __builtin_amdgcn_mfma_f32_16x16x32_bf16(areg[nt][cs], bfrag[cs], acc[nt][kt], 0, 0, 0);
    }
}

// ---- single-sweep MFMA prefilter: barrier-free k-loop, monotone LDS running min,
// ---- seeded thresholds, block candidate buffer, exact fp32 rescore ----
// __launch_bounds__(256,2): 256-VGPR cap -- (256,3) spilled areg/acc to scratch (R4: 1.5GB fetch)
__global__ __launch_bounds__(256, 2) void k_mfma_argmin(
    const ushort* __restrict__ zb, const ushort* __restrict__ cbb,
    const float* __restrict__ z, const float* __restrict__ cb,
    const float* __restrict__ srow, const float* __restrict__ ckg,
    int* __restrict__ indices, int* __restrict__ cntK)
{
    __shared__ unsigned rowminU[64];
    __shared__ int   candRK[CAP];
    __shared__ float candD[CAP];
    __shared__ int   cnt;
    __shared__ float thrF[64];
    __shared__ unsigned long long best[64];

    const int tid = threadIdx.x;
    const int w = tid >> 6, lane = tid & 63;
    const int col = lane & 15, quad = lane >> 4;
    const int n0 = blockIdx.x * 64;

    // A fragments: lane holds A[row=col][c=quad*8..+7] for 4 row-tiles
    short8 areg[4][8];
#pragma unroll
    for (int nt = 0; nt < 4; ++nt)
#pragma unroll
        for (int cs = 0; cs < 8; ++cs)
            areg[nt][cs] = *(const short8*)(zb + ((size_t)(n0 + nt * 16 + col)) * CDIM + cs * 32 + quad * 8);

    if (tid < 64) { rowminU[tid] = 0xFFFFFFFFu; best[tid] = ~0ull; }
    if (tid == 0) cnt = 0;
    float gmin[16];
#pragma unroll
    for (int s = 0; s < 16; ++s) gmin[s] = INFINITY;
    __syncthreads();

    // seed tile (k0=0, update-only): prevents tile-0 candidate flood
    {
        f32x4 acc[4][2];
        tile_mfma(cbb, w * 32, col, quad, areg, acc);
#pragma unroll
        for (int kt = 0; kt < 2; ++kt) {
            const float ckv = ckg[w * 32 + kt * 16 + col];
#pragma unroll
            for (int nt = 0; nt < 4; ++nt)
#pragma unroll
                for (int r = 0; r < 4; ++r) {
                    float dt = fmaf(-2.0f, acc[nt][kt][r], ckv);
                    const int s = nt * 4 + r;
                    if (dt < gmin[s]) {
                        gmin[s] = dt;
                        atomicMin(&rowminU[nt * 16 + quad * 4 + r], enc_f(dt));
                    }
                }
        }
    }
    __syncthreads();   // one-time: seed visible; later staleness is superset-safe (monotone min)

    int npass = 1;
    float thr[16];
    for (int pass = 0; pass < npass; ++pass) {
        for (int k0 = 0; k0 < KCB; k0 += 128) {
            const int kb = k0 + w * 32;
            if (pass == 0) {
                // refresh running thresholds (any stale value >= final min)
#pragma unroll
                for (int s = 0; s < 16; ++s) {
                    int row = (s >> 2) * 16 + quad * 4 + (s & 3);
                    gmin[s] = fminf(gmin[s], dec_f(rowminU[row]));
                }
            }
            f32x4 acc[4][2];
            tile_mfma(cbb, kb, col, quad, areg, acc);
#pragma unroll
            for (int kt = 0; kt < 2; ++kt) {
                const int k = kb + kt * 16 + col;
                const float ckv = ckg[k];
#pragma unroll
                for (int nt = 0; nt < 4; ++nt)
#pragma unroll
                    for (int r = 0; r < 4; ++r) {
                        float dt = fmaf(-2.0f, acc[nt][kt][r], ckv);
                        const int s = nt * 4 + r;
                        const int row = nt * 16 + quad * 4 + r;
                        if (pass == 0) {
                            if (dt < gmin[s]) {
                                gmin[s] = dt;
                                atomicMin(&rowminU[row], enc_f(dt));
                            }
                            if (dt <= gmin[s] + MARGIN) {
                                int p = atomicAdd(&cnt, 1);
                                if (p < CAP) { candRK[p] = (row << 16) | k; candD[p] = dt; }
                            }
                        } else if (dt <= thr[s]) {
                            int p = atomicAdd(&cnt, 1);
                            if (p < CAP) { candRK[p] = (row << 16) | k; candD[p] = dt; }
                        }
                    }
            }
        }
        __syncthreads();
        if (pass == 0) {
#pragma unroll
            for (int s = 0; s < 16; ++s)
                thr[s] = dec_f(rowminU[(s >> 2) * 16 + quad * 4 + (s & 3)]) + MARGIN;
            if (cnt > CAP) {   // overflow (expected never): re-collect with final thresholds
                npass = 2;
                __syncthreads();
                if (tid == 0) cnt = 0;
                __syncthreads();
            }
        }
    }
    if (tid < 64) thrF[tid] = dec_f(rowminU[tid]) + MARGIN;
    __syncthreads();

    // exact fp32 rescore (identical formula/order to round-1 validated kernel)
    const int b = n0 >> 10, hw0 = n0 & 1023;
    const int nc = min(cnt, CAP);
    for (int t = tid; t < nc; t += 256) {
        const int rc = candRK[t];
        const int row = rc >> 16, k = rc & 0xFFFF;
        if (candD[t] > thrF[row]) continue;   // trim stale-threshold over-collection
        const float* zp = z + (size_t)b * (CDIM * HW) + hw0 + row;
        const float* cp = cb + (size_t)k * CDIM;
        float m = 0.f;
#pragma unroll 8
        for (int c = 0; c < CDIM; ++c) m = fmaf(zp[(size_t)c << 10], cp[c], m);
        float d = (srow[n0 + row] - 2.0f * m) + ckg[k];   // 2m exact -> fma contraction bitwise-safe
        unsigned long long pk = ((unsigned long long)__float_as_uint(d) << 32) | (unsigned)k;
        lds_min_u64(&best[row], pk);   // d>=0: bit-order == float order; low bits: lowest-k tie
    }
    __syncthreads();
    if (tid < 64) {
        int bk = (int)(best[tid] & 0xFFFFFFFFull);
        indices[n0 + tid] = bk;
        atomicAdd(&cntK[bk], 1);
    }
}

// coalesced gather: block owns 64 rows; stage their codebook rows in LDS transposed
__global__ __launch_bounds__(256, 2) void k_gather(const float* __restrict__ z, const float* __restrict__ cb,
                                                   const int* __restrict__ idx, float* __restrict__ out0,
                                                   double* __restrict__ part) {
    __shared__ float qt[CDIM * 64];   // qt[c][n] 64 KB
    __shared__ double sh[256];
    const int tid = threadIdx.x;
    const int nl = tid & 63, cg = tid >> 6;
    const int n0 = blockIdx.x * 64;
    const int b = n0 >> 10, hw0 = n0 & 1023;
    const int k = idx[n0 + nl];
    const float* crow = cb + (size_t)k * CDIM + cg * 64;
#pragma unroll
    for (int j4 = 0; j4 < 16; ++j4) {
        float4 v = *(const float4*)(crow + j4 * 4);
        int c = cg * 64 + j4 * 4;
        qt[(c + 0) * 64 + nl] = v.x;
        qt[(c + 1) * 64 + nl] = v.y;
        qt[(c + 2) * 64 + nl] = v.z;
        qt[(c + 3) * 64 + nl] = v.w;
    }
    __syncthreads();
    double acc = 0.0;
    const size_t ebase = ((size_t)b * CDIM) * HW + hw0 + nl;
#pragma unroll 4
    for (int j = 0; j < 64; ++j) {
        int c = cg * 64 + j;
        size_t e = ebase + ((size_t)c << 10);
        float ze = z[e];
        float q = qt[c * 64 + nl];
        float d = q - ze;
        out0[e] = ze + d;
        acc += (double)d * (double)d;
    }
    sh[tid] = acc;
    __syncthreads();
    for (int s = 128; s > 0; s >>= 1) {
        if (tid < s) sh[tid] += sh[tid + s];
        __syncthreads();
    }
    if (tid == 0) part[blockIdx.x] = sh[0];
}

// fused zero + one-hot scatter over [OUT_LOSS, end) as float4 (16B-aligned anchor)
__global__ __launch_bounds__(256) void k_encodings(const int* __restrict__ idx, float4* __restrict__ p4,
                                                   float* __restrict__ tail) {
    __shared__ int sidx[17];
    const int tid = threadIdx.x;
    const size_t g0 = (size_t)blockIdx.x * 8192;
    const long f0 = 4L * (long)g0 - 2;
    int nlo = (int)(f0 >> 11); if (nlo < 0) nlo = 0;
    if (tid < 17) { int n = nlo + tid; sidx[tid] = (n < NTOT) ? idx[n] : -1; }
    __syncthreads();
    const float4 zv = make_float4(0.f, 0.f, 0.f, 0.f);
    for (int i = 0; i < 32; ++i) {
        size_t g = g0 + (size_t)i * 256 + tid;
        long fe = 4L * (long)g - 2;
        float4 v = zv;
        if (fe < 0) {
            // g==0: comps 0,1 = loss/perp (finalize rewrites), comps 2,3 = enc[n=0][k=0,1]
            int kk = sidx[0];
            if (kk == 0) v.z = 1.f;
            if (kk == 1) v.w = 1.f;
        } else {
            int n = (int)(fe >> 11);
            int k0c = (int)(fe & 2047);
            if (k0c >= 2045) {   // f4 straddles a row boundary
#pragma unroll
                for (int j = 0; j < 4; ++j) {
                    long fej = fe + j;
                    int nj = (int)(fej >> 11);
                    int kj = (int)(fej & 2047);
                    int li = nj - nlo;
                    int kk = (li >= 0 && li < 17) ? sidx[li] : -2;
                    ((float*)&v)[j] = (kk == kj) ? 1.f : 0.f;
                }
            } else {
                int d = sidx[n - nlo] - k0c;
                if (d >= 0 && d < 4) ((float*)&v)[d] = 1.f;
            }
        }
        p4[g] = v;
    }
    if (blockIdx.x == 0 && tid == 0) {
        // last 2 floats of out = enc[n=65535][k=2046,2047]
        int kk = idx[NTOT - 1];
        tail[0] = (kk == 2046) ? 1.f : 0.f;
        tail[1] = (kk == 2047) ? 1.f : 0.f;
    }
}

__global__ __launch_bounds__(256) void k_finalize(const double* __restrict__ part, const int* __restrict__ cnt,
                                                  float* __restrict__ out) {
    __shared__ double sh[256];
    double a = 0.0;
    for (int i = threadIdx.x; i < 1024; i += 256) a += part[i];
    sh[threadIdx.x] = a; __syncthreads();
    for (int s = 128; s > 0; s >>= 1) { if (threadIdx.x < s) sh[threadIdx.x] += sh[threadIdx.x + s]; __syncthreads(); }
    double total = sh[0];
    __syncthreads();
    double p = 0.0;
    for (int i = threadIdx.x; i < 2048; i += 256) {
        double pm = (double)cnt[i] / 65536.0;
        p += pm * log(pm + 1e-10);
    }
    sh[threadIdx.x] = p; __syncthreads();
    for (int s = 128; s > 0; s >>= 1) { if (threadIdx.x < s) sh[threadIdx.x] += sh[threadIdx.x + s]; __syncthreads(); }
    if (threadIdx.x == 0) {
        double mean = total / ((double)NTOT * (double)CDIM);
        out[OUT_LOSS] = (float)(mean * 1.25);
        out[OUT_PERP] = (float)exp(-sh[0]);
    }
}

extern "C" void kernel_launch(void* const* d_in, const int* in_sizes, int n_in,
                              void* d_out, int out_size, void* d_ws, size_t ws_size,
                              hipStream_t stream) {
    const float* z  = (const float*)d_in[0];
    const float* cb = (const float*)d_in[1];
    float* out = (float*)d_out;
    char* ws = (char*)d_ws;
    float*  srow = (float*)(ws + WS_SROW);
    float*  ck   = (float*)(ws + WS_CK);
    int*    idx  = (int*)(ws + WS_IDX);
    int*    cnt  = (int*)(ws + WS_CNT);
    double* part = (double*)(ws + WS_PART);
    ushort* zb  = (ushort*)(out + ZB_OFF_F);
    ushort* cbb = (ushort*)(out + CBB_OFF_F);

    hipLaunchKernelGGL(k_prep,        dim3(4864), dim3(256), 0, stream, z, cb, zb, cbb, ck, srow, cnt);
    hipLaunchKernelGGL(k_mfma_argmin, dim3(1024), dim3(256), 0, stream, zb, cbb, z, cb, srow, ck, idx, cnt);
    hipLaunchKernelGGL(k_gather,      dim3(1024), dim3(256), 0, stream, z, cb, idx, out, part);
    hipLaunchKernelGGL(k_encodings,   dim3(4096), dim3(256), 0, stream, idx, (float4*)(out + OUT_LOSS),
                       out + (OUT_LOSS + (size_t)33554432 * 4));
    hipLaunchKernelGGL(k_finalize,    dim3(1),    dim3(256), 0, stream, part, cnt, out);
}

// Round 6
// 925.964 us; speedup vs baseline: 1.5873x; 1.0841x over previous
//
#include <hip/hip_runtime.h>
#include <hip/hip_bf16.h>
#include <math.h>

#define NTOT 65536
#define KCB  2048
#define CDIM 256
#define HW   1024

#define OUT_LOSS 16777216
#define OUT_PERP 16777217
#define OUT_ENC  16777218

// bf16 staging lives in the (later overwritten) encodings output region:
#define ZB_OFF_F  16777232   // 64B-aligned; 33.5 MB zb [65536][256] bf16
#define CBB_OFF_F 33554448   // 1 MB cbb [2048][256] bf16

// workspace byte offsets
#define WS_SROW 0                       // 65536 float
#define WS_CK   262144                  // 2048 float
#define WS_IDX  270336                  // 65536 int
#define WS_CNT  532480                  // 2048 int
#define WS_PART 540672                  // 1024 double

#define MARGIN 3e-3f
#define CAP 2048

typedef __attribute__((ext_vector_type(8))) short short8;
typedef __attribute__((ext_vector_type(4))) float f32x4;

// order-preserving float<->uint key (handles negative d~)
__device__ inline unsigned enc_f(float x) {
    unsigned u = __float_as_uint(x);
    return (u & 0x80000000u) ? ~u : (u | 0x80000000u);
}
__device__ inline float dec_f(unsigned e) {
    unsigned u = (e & 0x80000000u) ? (e ^ 0x80000000u) : ~e;
    return __uint_as_float(u);
}

__device__ inline void lds_min_u64(unsigned long long* p, unsigned long long v) {
    unsigned long long old = *p;
    while (v < old) {
        unsigned long long assumed = old;
        old = atomicCAS(p, assumed, v);
        if (old == assumed) break;
    }
}

// merged prep: blocks [0,512) cb->bf16+norms+hist-zero; [512,768) rownorm; [768,4864) z->bf16 transpose
__global__ __launch_bounds__(256) void k_prep(const float* __restrict__ z, const float* __restrict__ cb,
                                              ushort* __restrict__ zb, ushort* __restrict__ cbb,
                                              float* __restrict__ ck, float* __restrict__ srow,
                                              int* __restrict__ cntK) {
    __shared__ float tile[64][65];
    const int tid = threadIdx.x;
    const int bid = blockIdx.x;
    if (bid < 512) {
        int wv = tid >> 6, lane = tid & 63;
        int r = bid * 4 + wv;
        const float* row = cb + (size_t)r * CDIM;
        float4 v = *(const float4*)(row + lane * 4);
        ushort4 o;
        __hip_bfloat16 h;
        h = __float2bfloat16(v.x); o.x = *(ushort*)&h;
        h = __float2bfloat16(v.y); o.y = *(ushort*)&h;
        h = __float2bfloat16(v.z); o.z = *(ushort*)&h;
        h = __float2bfloat16(v.w); o.w = *(ushort*)&h;
        *(ushort4*)(cbb + (size_t)r * CDIM + lane * 4) = o;
        float s = v.x*v.x + v.y*v.y + v.z*v.z + v.w*v.w;
        for (int off = 32; off >= 1; off >>= 1) s += __shfl_down(s, off, 64);
        if (lane == 0) ck[r] = s;
        if (lane == 1) cntK[r] = 0;
    } else if (bid < 768) {
        // srow: EXACT sequential-fma order validated in round 1
        int n = (bid - 512) * 256 + tid;
        int b = n >> 10, hw = n & 1023;
        const float* base = z + (size_t)b * (CDIM * HW) + hw;
        float s = 0.f;
#pragma unroll 8
        for (int c = 0; c < CDIM; ++c) { float v = base[(size_t)c * HW]; s = fmaf(v, v, s); }
        srow[n] = s;
    } else {
        int zbid = bid - 768;
        int hwT = zbid & 15, cT = (zbid >> 4) & 3, b = zbid >> 6;
        int c0 = cT * 64, hw0 = hwT * 64;
        int w = tid >> 6, hw = tid & 63;
#pragma unroll
        for (int l = 0; l < 16; ++l) {
            int c = l * 4 + w;
            tile[c][hw] = z[((size_t)b * CDIM + (c0 + c)) * HW + hw0 + hw];
        }
        __syncthreads();
        int r = tid >> 2, g = tid & 3;
        union { ushort u[16]; int4 v[2]; } pk;
#pragma unroll
        for (int j = 0; j < 16; ++j) {
            __hip_bfloat16 h = __float2bfloat16(tile[g * 16 + j][r]);
            pk.u[j] = *(ushort*)&h;
        }
        size_t n = (size_t)b * HW + hw0 + r;
        ushort* dst = zb + n * CDIM + c0 + g * 16;
        *(int4*)(dst) = pk.v[0];
        *(int4*)(dst + 8) = pk.v[1];
    }
}

// ---- MFMA prefilter with branchless per-thread (m1,k1,m2) tracking + exact rescore ----
// k-loop has ZERO LDS ops / atomics / branches: 6 VALU per element epilogue.
// Provable margin completeness: a margin-k is either some lane's m1 (pushed) or hidden
// behind its lane's m1 -> that lane's m2 <= thr -> push the lane's whole 32-k subset.
__global__ __launch_bounds__(256, 2) void k_mfma_argmin(
    const ushort* __restrict__ zb, const ushort* __restrict__ cbb,
    const float* __restrict__ z, const float* __restrict__ cb,
    const float* __restrict__ srow, const float* __restrict__ ckg,
    int* __restrict__ indices, int* __restrict__ cntK)
{
    __shared__ unsigned long long wmin[4][64];
    __shared__ float thrRow[64];
    __shared__ int   candRK[CAP];
    __shared__ int   cnt;
    __shared__ int   allscan;
    __shared__ unsigned long long best[64];

    const int tid = threadIdx.x;
    const int w = tid >> 6, lane = tid & 63;
    const int col = lane & 15, quad = lane >> 4;
    const int n0 = blockIdx.x * 64;

    // A fragments: lane holds A[row=col][c=quad*8..+7] for 4 row-tiles (128 VGPRs)
    short8 areg[4][8];
#pragma unroll
    for (int nt = 0; nt < 4; ++nt)
#pragma unroll
        for (int cs = 0; cs < 8; ++cs)
            areg[nt][cs] = *(const short8*)(zb + ((size_t)(n0 + nt * 16 + col)) * CDIM + cs * 32 + quad * 8);

    float m1[16], m2[16]; int k1[16];
#pragma unroll
    for (int s = 0; s < 16; ++s) { m1[s] = INFINITY; m2[s] = INFINITY; k1[s] = 0; }

    for (int k0 = 0; k0 < KCB; k0 += 128) {
        const int kb = k0 + w * 32;
#pragma unroll
        for (int kt = 0; kt < 2; ++kt) {
            const int kk = kb + kt * 16 + col;
            const ushort* bbase = cbb + (size_t)kk * CDIM + quad * 8;
            short8 bfrag[8];
#pragma unroll
            for (int cs = 0; cs < 8; ++cs) bfrag[cs] = *(const short8*)(bbase + cs * 32);
            f32x4 acc[4];
#pragma unroll
            for (int nt = 0; nt < 4; ++nt) acc[nt] = (f32x4){0.f, 0.f, 0.f, 0.f};
#pragma unroll
            for (int cs = 0; cs < 8; ++cs)
#pragma unroll
                for (int nt = 0; nt < 4; ++nt)
                    acc[nt] = __builtin_amdgcn_mfma_f32_16x16x32_bf16(areg[nt][cs], bfrag[cs], acc[nt], 0, 0, 0);
            const float ckv = ckg[kk];
#pragma unroll
            for (int nt = 0; nt < 4; ++nt)
#pragma unroll
                for (int r = 0; r < 4; ++r) {
                    float dt = fmaf(-2.0f, acc[nt][r], ckv);
                    const int s = nt * 4 + r;
                    bool c = dt < m1[s];
                    m2[s] = fminf(m2[s], fmaxf(dt, m1[s]));   // 2nd-smallest of lane's values
                    m1[s] = fminf(m1[s], dt);
                    k1[s] = c ? kk : k1[s];
                }
        }
    }

    // per-row min: butterfly over the 16 col-lanes (u64 packed: lowest-k tie), then cross-wave via LDS
#pragma unroll
    for (int s = 0; s < 16; ++s) {
        unsigned long long v = ((unsigned long long)enc_f(m1[s]) << 32) | (unsigned)k1[s];
#pragma unroll
        for (int m = 1; m <= 8; m <<= 1) {
            unsigned long long o = __shfl_xor(v, m, 64);
            v = (o < v) ? o : v;
        }
        if (col == 0) wmin[w][(s >> 2) * 16 + quad * 4 + (s & 3)] = v;
    }
    if (tid == 0) { cnt = 0; allscan = 0; }
    if (tid < 64) best[tid] = ~0ull;
    __syncthreads();
    if (tid < 64) {
        unsigned long long v = wmin[0][tid];
        unsigned long long o = wmin[1][tid]; v = (o < v) ? o : v;
        o = wmin[2][tid]; v = (o < v) ? o : v;
        o = wmin[3][tid]; v = (o < v) ? o : v;
        thrRow[tid] = dec_f((unsigned)(v >> 32)) + MARGIN;
    }
    __syncthreads();

    // push candidates; flagged lanes (m2 within margin) push their whole 32-k subset
#pragma unroll
    for (int s = 0; s < 16; ++s) {
        const int row = (s >> 2) * 16 + quad * 4 + (s & 3);
        const float thr = thrRow[row];
        if (m1[s] <= thr) {
            int p = atomicAdd(&cnt, 1);
            if (p < CAP) candRK[p] = (row << 16) | k1[s];
        }
        if (m2[s] <= thr) {
            const int kt = s & 1;   // any fixed mapping is wrong; push BOTH kt halves:
            (void)kt;
            int p = atomicAdd(&cnt, 32);
            if (p + 32 <= CAP) {
#pragma unroll
                for (int k0i = 0; k0i < 16; ++k0i) {
                    int kbase = k0i * 128 + w * 32 + col;
                    candRK[p + 2 * k0i]     = (row << 16) | kbase;
                    candRK[p + 2 * k0i + 1] = (row << 16) | (kbase + 16);
                }
            }
        }
    }
    __syncthreads();
    if (cnt > CAP) { if (tid == 0) allscan = 1; }
    __syncthreads();
    const int nc = allscan ? 0 : min(cnt, CAP);

    // exact fp32 rescore (identical formula/order to round-1 validated kernel)
    const int b = n0 >> 10, hw0 = n0 & 1023;
    for (int t = tid; t < nc; t += 256) {
        const int rc = candRK[t];
        const int row = rc >> 16, k = rc & 0xFFFF;
        const float* zp = z + (size_t)b * (CDIM * HW) + hw0 + row;
        const float* cp = cb + (size_t)k * CDIM;
        float m = 0.f;
#pragma unroll 8
        for (int c = 0; c < CDIM; ++c) m = fmaf(zp[(size_t)c << 10], cp[c], m);
        float d = (srow[n0 + row] - 2.0f * m) + ckg[k];   // 2m exact -> fma contraction bitwise-safe
        unsigned long long pk = ((unsigned long long)__float_as_uint(d) << 32) | (unsigned)k;
        lds_min_u64(&best[row], pk);   // d>=0: bit-order == float order; low bits: lowest-k tie
    }
    // overflow fallback (expected never): exact full scan of all rows
    if (allscan) {
        for (int row = 0; row < 64; ++row) {
            const float sr = srow[n0 + row];
            const float* zp = z + (size_t)b * (CDIM * HW) + hw0 + row;
            for (int kq = 0; kq < 8; ++kq) {
                int k = kq * 256 + tid;
                const float* cp = cb + (size_t)k * CDIM;
                float m = 0.f;
#pragma unroll 8
                for (int c = 0; c < CDIM; ++c) m = fmaf(zp[(size_t)c << 10], cp[c], m);
                float d = (sr - 2.0f * m) + ckg[k];
                unsigned long long pk = ((unsigned long long)__float_as_uint(d) << 32) | (unsigned)k;
                lds_min_u64(&best[row], pk);
            }
        }
    }
    __syncthreads();
    if (tid < 64) {
        int bk = (int)(best[tid] & 0xFFFFFFFFull);
        indices[n0 + tid] = bk;
        atomicAdd(&cntK[bk], 1);
    }
}

// coalesced gather: block owns 64 rows; stage their codebook rows in LDS transposed
__global__ __launch_bounds__(256, 2) void k_gather(const float* __restrict__ z, const float* __restrict__ cb,
                                                   const int* __restrict__ idx, float* __restrict__ out0,
                                                   double* __restrict__ part) {
    __shared__ float qt[CDIM * 64];   // qt[c][n] 64 KB
    __shared__ double sh[256];
    const int tid = threadIdx.x;
    const int nl = tid & 63, cg = tid >> 6;
    const int n0 = blockIdx.x * 64;
    const int b = n0 >> 10, hw0 = n0 & 1023;
    const int k = idx[n0 + nl];
    const float* crow = cb + (size_t)k * CDIM + cg * 64;
#pragma unroll
    for (int j4 = 0; j4 < 16; ++j4) {
        float4 v = *(const float4*)(crow + j4 * 4);
        int c = cg * 64 + j4 * 4;
        qt[(c + 0) * 64 + nl] = v.x;
        qt[(c + 1) * 64 + nl] = v.y;
        qt[(c + 2) * 64 + nl] = v.z;
        qt[(c + 3) * 64 + nl] = v.w;
    }
    __syncthreads();
    double acc = 0.0;
    const size_t ebase = ((size_t)b * CDIM) * HW + hw0 + nl;
#pragma unroll 4
    for (int j = 0; j < 64; ++j) {
        int c = cg * 64 + j;
        size_t e = ebase + ((size_t)c << 10);
        float ze = z[e];
        float q = qt[c * 64 + nl];
        float d = q - ze;
        out0[e] = ze + d;
        acc += (double)d * (double)d;
    }
    sh[tid] = acc;
    __syncthreads();
    for (int s = 128; s > 0; s >>= 1) {
        if (tid < s) sh[tid] += sh[tid + s];
        __syncthreads();
    }
    if (tid == 0) part[blockIdx.x] = sh[0];
}

// fused zero + one-hot scatter over [OUT_LOSS, end) as float4 (16B-aligned anchor)
__global__ __launch_bounds__(256) void k_encodings(const int* __restrict__ idx, float4* __restrict__ p4,
                                                   float* __restrict__ tail) {
    __shared__ int sidx[17];
    const int tid = threadIdx.x;
    const size_t g0 = (size_t)blockIdx.x * 8192;
    const long f0 = 4L * (long)g0 - 2;
    int nlo = (int)(f0 >> 11); if (nlo < 0) nlo = 0;
    if (tid < 17) { int n = nlo + tid; sidx[tid] = (n < NTOT) ? idx[n] : -1; }
    __syncthreads();
    const float4 zv = make_float4(0.f, 0.f, 0.f, 0.f);
    for (int i = 0; i < 32; ++i) {
        size_t g = g0 + (size_t)i * 256 + tid;
        long fe = 4L * (long)g - 2;
        float4 v = zv;
        if (fe < 0) {
            // g==0: comps 0,1 = loss/perp (finalize rewrites), comps 2,3 = enc[n=0][k=0,1]
            int kk = sidx[0];
            if (kk == 0) v.z = 1.f;
            if (kk == 1) v.w = 1.f;
        } else {
            int n = (int)(fe >> 11);
            int k0c = (int)(fe & 2047);
            if (k0c >= 2045) {   // f4 straddles a row boundary
#pragma unroll
                for (int j = 0; j < 4; ++j) {
                    long fej = fe + j;
                    int nj = (int)(fej >> 11);
                    int kj = (int)(fej & 2047);
                    int li = nj - nlo;
                    int kk = (li >= 0 && li < 17) ? sidx[li] : -2;
                    ((float*)&v)[j] = (kk == kj) ? 1.f : 0.f;
                }
            } else {
                int d = sidx[n - nlo] - k0c;
                if (d >= 0 && d < 4) ((float*)&v)[d] = 1.f;
            }
        }
        p4[g] = v;
    }
    if (blockIdx.x == 0 && tid == 0) {
        // last 2 floats of out = enc[n=65535][k=2046,2047]
        int kk = idx[NTOT - 1];
        tail[0] = (kk == 2046) ? 1.f : 0.f;
        tail[1] = (kk == 2047) ? 1.f : 0.f;
    }
}

__global__ __launch_bounds__(256) void k_finalize(const double* __restrict__ part, const int* __restrict__ cnt,
                                                  float* __restrict__ out) {
    __shared__ double sh[256];
    double a = 0.0;
    for (int i = threadIdx.x; i < 1024; i += 256) a += part[i];
    sh[threadIdx.x] = a; __syncthreads();
    for (int s = 128; s > 0; s >>= 1) { if (threadIdx.x < s) sh[threadIdx.x] += sh[threadIdx.x + s]; __syncthreads(); }
    double total = sh[0];
    __syncthreads();
    double p = 0.0;
    for (int i = threadIdx.x; i < 2048; i += 256) {
        double pm = (double)cnt[i] / 65536.0;
        p += pm * log(pm + 1e-10);
    }
    sh[threadIdx.x] = p; __syncthreads();
    for (int s = 128; s > 0; s >>= 1) { if (threadIdx.x < s) sh[threadIdx.x] += sh[threadIdx.x + s]; __syncthreads(); }
    if (threadIdx.x == 0) {
        double mean = total / ((double)NTOT * (double)CDIM);
        out[OUT_LOSS] = (float)(mean * 1.25);
        out[OUT_PERP] = (float)exp(-sh[0]);
    }
}

extern "C" void kernel_launch(void* const* d_in, const int* in_sizes, int n_in,
                              void* d_out, int out_size, void* d_ws, size_t ws_size,
                              hipStream_t stream) {
    const float* z  = (const float*)d_in[0];
    const float* cb = (const float*)d_in[1];
    float* out = (float*)d_out;
    char* ws = (char*)d_ws;
    float*  srow = (float*)(ws + WS_SROW);
    float*  ck   = (float*)(ws + WS_CK);
    int*    idx  = (int*)(ws + WS_IDX);
    int*    cnt  = (int*)(ws + WS_CNT);
    double* part = (double*)(ws + WS_PART);
    ushort* zb  = (ushort*)(out + ZB_OFF_F);
    ushort* cbb = (ushort*)(out + CBB_OFF_F);

    hipLaunchKernelGGL(k_prep,        dim3(4864), dim3(256), 0, stream, z, cb, zb, cbb, ck, srow, cnt);
    hipLaunchKernelGGL(k_mfma_argmin, dim3(1024), dim3(256), 0, stream, zb, cbb, z, cb, srow, ck, idx, cnt);
    hipLaunchKernelGGL(k_gather,      dim3(1024), dim3(256), 0, stream, z, cb, idx, out, part);
    hipLaunchKernelGGL(k_encodings,   dim3(4096), dim3(256), 0, stream, idx, (float4*)(out + OUT_LOSS),
                       out + (OUT_LOSS + (size_t)33554432 * 4));
    hipLaunchKernelGGL(k_finalize,    dim3(1),    dim3(256), 0, stream, part, cnt, out);
}